// Round 1
// baseline (1873.848 us; speedup 1.0000x reference)
//
#include <hip/hip_runtime.h>
#include <math.h>

#define BB 16
#define TT 512
#define IND 128
#define HH 256
#define DD 8
#define EPSF 1e-5f

// ---------------- K1: x_proj[b,t,j] = y[b,t,:]·W_ih[j,:] + b_ih[j] + b_hh[j] ----------------
// 512 blocks x 256 threads; each block does 16 (b,t) rows; W_ih row kept in VGPRs.
__global__ __launch_bounds__(256) void xproj_kernel(
    const float* __restrict__ y, const float* __restrict__ W_ih,
    const float* __restrict__ b_ih, const float* __restrict__ b_hh,
    float* __restrict__ xp)
{
    __shared__ float4 ylds[IND / 4];  // 32 float4 = one y row
    const int j = threadIdx.x;

    float4 w[IND / 4];
    const float4* wr = (const float4*)(W_ih + (size_t)j * IND);
#pragma unroll
    for (int i = 0; i < IND / 4; ++i) w[i] = wr[i];
    const float bias = b_ih[j] + b_hh[j];

    const int row0 = blockIdx.x * 16;
    for (int r = 0; r < 16; ++r) {
        const int row = row0 + r;
        if (j < IND / 4) ylds[j] = ((const float4*)(y + (size_t)row * IND))[j];
        __syncthreads();
        float a0 = 0.f, a1 = 0.f, a2 = 0.f, a3 = 0.f;
#pragma unroll
        for (int i = 0; i < IND / 4; ++i) {
            float4 hv = ylds[i];
            a0 += hv.x * w[i].x;
            a1 += hv.y * w[i].y;
            a2 += hv.z * w[i].z;
            a3 += hv.w * w[i].w;
        }
        xp[(size_t)row * HH + j] = ((a0 + a1) + (a2 + a3)) + bias;
        __syncthreads();
    }
}

// ---------------- K2: RNN scan (blocks 0..15) + prec zero-fill (blocks 16..255) ----------------
// Scan: one block per batch. Thread j holds W_hh[j,:] in 256 VGPRs. h double-buffered in LDS,
// broadcast ds_read_b128; 4 independent FMA chains; one barrier per step.
__global__ __launch_bounds__(256, 1) void scan_fill_kernel(
    const float* __restrict__ xp, const float* __restrict__ W_hh,
    float* __restrict__ enc, float* __restrict__ prec)
{
    if (blockIdx.x >= BB) {
        // zero-fill the 128 MB prec tensor with float4 stores
        const size_t n4 = (size_t)BB * DD * TT * TT / 4;  // 8388608
        float4 z = make_float4(0.f, 0.f, 0.f, 0.f);
        float4* p4 = (float4*)prec;
        size_t idx = (size_t)(blockIdx.x - BB) * blockDim.x + threadIdx.x;
        const size_t stride = (size_t)(gridDim.x - BB) * blockDim.x;
        for (; idx < n4; idx += stride) p4[idx] = z;
        return;
    }

    const int b = blockIdx.x;
    const int j = threadIdx.x;
    __shared__ __align__(16) float hbuf[2][HH];

    float4 w[HH / 4];
    const float4* wr = (const float4*)(W_hh + (size_t)j * HH);
#pragma unroll
    for (int i = 0; i < HH / 4; ++i) w[i] = wr[i];

    hbuf[0][j] = 0.f;
    __syncthreads();

    const float* xpb = xp + (size_t)b * TT * HH;
    float* encb = enc + (size_t)b * TT * HH;

    int cur = 0;
    float xc = xpb[j];  // t = 0
    for (int t = 0; t < TT; ++t) {
        // prefetch next step's x_proj early (hidden under the dot product)
        const int tn = (t < TT - 1) ? t + 1 : t;
        const float xn = xpb[(size_t)tn * HH + j];

        float a0 = 0.f, a1 = 0.f, a2 = 0.f, a3 = 0.f;
        const float4* hb = (const float4*)hbuf[cur];
#pragma unroll
        for (int i = 0; i < HH / 4; ++i) {
            float4 hv = hb[i];
            a0 += hv.x * w[i].x;
            a1 += hv.y * w[i].y;
            a2 += hv.z * w[i].z;
            a3 += hv.w * w[i].w;
        }
        const float acc = xc + ((a0 + a1) + (a2 + a3));
        const float hn = tanhf(acc);
        encb[(size_t)t * HH + j] = hn;
        hbuf[cur ^ 1][j] = hn;
        __syncthreads();
        cur ^= 1;
        xc = xn;
    }
}

// ---------------- K3: heads + tridiagonal fill ----------------
// One block per (b,t). 32 groups of 8 lanes each compute one 256-dot:
//   g 0..7  : mean_d   = enc[t]·W_mean[d] + b_mean[d]
//   g 8..15 : diag_d   = enc[t]·W_bd[d]   + b_bd[d]
//   g 16..23: off_d    = enc[t]·W_bd[8+d] + b_bd[8+d]
//   g 24..31: offp_d   = enc[t-1]·W_bd[8+d] + b_bd[8+d]   (t>0)
__global__ __launch_bounds__(256) void head_kernel(
    const float* __restrict__ enc,
    const float* __restrict__ W_mean, const float* __restrict__ b_mean,
    const float* __restrict__ W_bd, const float* __restrict__ b_bd,
    float* __restrict__ mean_out, float* __restrict__ prec)
{
    const int b = blockIdx.x >> 9;
    const int t = blockIdx.x & (TT - 1);
    __shared__ __align__(16) float4 ec[HH / 4];
    __shared__ __align__(16) float4 ep[HH / 4];
    __shared__ float vals[32];

    const int tid = threadIdx.x;
    const float* encb = enc + ((size_t)b * TT + t) * HH;
    if (tid < 64) {
        ec[tid] = ((const float4*)encb)[tid];
    } else if (tid < 128) {
        if (t > 0) ep[tid - 64] = ((const float4*)(encb - HH))[tid - 64];
    }
    __syncthreads();

    const int g = tid >> 3, m = tid & 7;
    const float* wrow;
    float bias;
    const float4* src;
    if (g < 8) {
        wrow = W_mean + (size_t)g * HH; bias = b_mean[g]; src = ec;
    } else if (g < 24) {
        wrow = W_bd + (size_t)(g - 8) * HH; bias = b_bd[g - 8]; src = ec;
    } else {
        wrow = W_bd + (size_t)(g - 16) * HH; bias = b_bd[g - 16]; src = ep;
    }

    float acc = 0.f;
    if (g < 24 || t > 0) {
        const float4* w4 = (const float4*)wrow;
#pragma unroll
        for (int i = 0; i < 8; ++i) {
            float4 wv = w4[m * 8 + i];
            float4 hv = src[m * 8 + i];
            acc += wv.x * hv.x + wv.y * hv.y + wv.z * hv.z + wv.w * hv.w;
        }
    }
    acc += __shfl_xor(acc, 1);
    acc += __shfl_xor(acc, 2);
    acc += __shfl_xor(acc, 4);
    if (m == 0) vals[g] = acc + bias;
    __syncthreads();

    if (tid < DD) {
        mean_out[((size_t)b * TT + t) * DD + tid] = vals[tid];
    } else if (tid < 2 * DD) {
        const int d = tid - DD;
        const float diag = vals[8 + d];
        const float off = vals[16 + d];
        const float offp = (t > 0) ? vals[24 + d] : 0.f;
        const size_t rowbase = (((size_t)b * DD + d) * TT + t) * TT;
        prec[rowbase + t] = diag * diag + offp * offp + EPSF;
        if (t < TT - 1) {
            const float s = diag * off;
            prec[rowbase + t + 1] = s;                                 // (t, t+1)
            prec[(((size_t)b * DD + d) * TT + (t + 1)) * TT + t] = s;  // (t+1, t)
        }
    }
}

extern "C" void kernel_launch(void* const* d_in, const int* in_sizes, int n_in,
                              void* d_out, int out_size, void* d_ws, size_t ws_size,
                              hipStream_t stream) {
    const float* y      = (const float*)d_in[0];
    const float* W_ih   = (const float*)d_in[1];
    const float* W_hh   = (const float*)d_in[2];
    const float* b_ih   = (const float*)d_in[3];
    const float* b_hh   = (const float*)d_in[4];
    const float* W_mean = (const float*)d_in[5];
    const float* b_mean = (const float*)d_in[6];
    const float* W_bd   = (const float*)d_in[7];
    const float* b_bd   = (const float*)d_in[8];

    float* out  = (float*)d_out;
    float* mean = out;                              // B*T*D = 65536 floats
    float* prec = out + (size_t)BB * TT * DD;       // B*D*T*T = 33554432 floats

    float* xp  = (float*)d_ws;                      // B*T*H floats = 8 MB
    float* enc = xp + (size_t)BB * TT * HH;         // B*T*H floats = 8 MB

    xproj_kernel<<<512, 256, 0, stream>>>(y, W_ih, b_ih, b_hh, xp);
    scan_fill_kernel<<<256, 256, 0, stream>>>(xp, W_hh, enc, prec);
    head_kernel<<<BB * TT, 256, 0, stream>>>(enc, W_mean, b_mean, W_bd, b_bd, mean, prec);
}

// Round 2
// 580.777 us; speedup vs baseline: 3.2264x; 3.2264x over previous
//
#include <hip/hip_runtime.h>
#include <math.h>

#define BB 16
#define TT 512
#define IND 128
#define HH 256
#define DD 8
#define EPSF 1e-5f

__device__ __forceinline__ float fast_tanh(float x) {
    x = fminf(fmaxf(x, -15.f), 15.f);
    const float e = __expf(2.f * x);
    return __fdividef(e - 1.f, e + 1.f);
}

// ---------------- K1: x_proj[b,t,j] = y[b,t,:]·W_ih[j,:] + b_ih[j] + b_hh[j] ----------------
// 512 threads: j = tid>>1 (output), k = tid&1 (dot split). Each thread holds 64 floats of
// W_ih in 16 float4 VGPRs (guaranteed promotion), partials combined with one shfl_xor.
__global__ __launch_bounds__(512, 4) void xproj_kernel(
    const float* __restrict__ y, const float* __restrict__ W_ih,
    const float* __restrict__ b_ih, const float* __restrict__ b_hh,
    float* __restrict__ xp)
{
    __shared__ __align__(16) float ylds[IND];
    const int tid = threadIdx.x;
    const int j = tid >> 1, k = tid & 1;

    float4 w[16];
    const float* wr = W_ih + (size_t)j * IND + k * 4;
#pragma unroll
    for (int i = 0; i < 16; ++i) w[i] = *(const float4*)(wr + i * 8);
    const float bias = b_ih[j] + b_hh[j];

    const int row0 = blockIdx.x * 16;
    for (int r = 0; r < 16; ++r) {
        const int row = row0 + r;
        if (tid < IND / 4) ((float4*)ylds)[tid] = ((const float4*)(y + (size_t)row * IND))[tid];
        __syncthreads();
        float a0 = 0.f, a1 = 0.f, a2 = 0.f, a3 = 0.f;
#pragma unroll
        for (int i = 0; i < 16; ++i) {
            const float4 hv = *(const float4*)(ylds + i * 8 + k * 4);
            a0 += hv.x * w[i].x;
            a1 += hv.y * w[i].y;
            a2 += hv.z * w[i].z;
            a3 += hv.w * w[i].w;
        }
        float acc = (a0 + a1) + (a2 + a3);
        acc += __shfl_xor(acc, 1);
        if (k == 0) xp[(size_t)row * HH + j] = acc + bias;
        __syncthreads();
    }
}

// ---------------- K2: RNN scan (blocks 0..15) + prec zero-fill (blocks 16..) ----------------
// One block per batch, 1024 threads: j = tid>>2 (output element), k = tid&3 (dot split).
// Thread (j,k) holds W_hh[j, 16i+4k+e] in 16 float4 = 64 VGPRs. h double-buffered in LDS;
// interleaved k-layout keeps the broadcast ds_read_b128 conflict-free. Two shfl_xor combine
// the 4 partials in-wave; all 4 lanes compute tanh redundantly (no divergence); one
// barrier per step.
__global__ __launch_bounds__(1024, 4) void scan_fill_kernel(
    const float* __restrict__ xp, const float* __restrict__ W_hh,
    float* __restrict__ enc, float* __restrict__ prec)
{
    if (blockIdx.x >= BB) {
        // zero-fill the 128 MB prec tensor with float4 stores
        const size_t n4 = (size_t)BB * DD * TT * TT / 4;
        const float4 z = make_float4(0.f, 0.f, 0.f, 0.f);
        float4* p4 = (float4*)prec;
        size_t idx = (size_t)(blockIdx.x - BB) * blockDim.x + threadIdx.x;
        const size_t stride = (size_t)(gridDim.x - BB) * blockDim.x;
        for (; idx < n4; idx += stride) p4[idx] = z;
        return;
    }

    const int b = blockIdx.x;
    const int tid = threadIdx.x;
    const int j = tid >> 2, k = tid & 3;
    __shared__ __align__(16) float hbuf[2][HH];

    float4 w[16];
    const float* wr = W_hh + (size_t)j * HH + k * 4;
#pragma unroll
    for (int i = 0; i < 16; ++i) w[i] = *(const float4*)(wr + i * 16);

    if (tid < HH) hbuf[0][tid] = 0.f;
    __syncthreads();

    const float* xpb = xp + (size_t)b * TT * HH;
    float* encb = enc + (size_t)b * TT * HH;

    int cur = 0;
    float xc = xpb[j];  // t = 0
    for (int t = 0; t < TT; ++t) {
        // prefetch next step's x_proj (hidden under the dot product)
        const int tn = (t < TT - 1) ? t + 1 : t;
        const float xn = xpb[(size_t)tn * HH + j];

        float a0 = 0.f, a1 = 0.f, a2 = 0.f, a3 = 0.f;
        const float* hb = hbuf[cur];
#pragma unroll
        for (int i = 0; i < 16; ++i) {
            const float4 hv = *(const float4*)(hb + i * 16 + k * 4);
            a0 += hv.x * w[i].x;
            a1 += hv.y * w[i].y;
            a2 += hv.z * w[i].z;
            a3 += hv.w * w[i].w;
        }
        float p = (a0 + a1) + (a2 + a3);
        p += __shfl_xor(p, 1);
        p += __shfl_xor(p, 2);
        const float hn = fast_tanh(xc + p);
        if (k == 0) {
            hbuf[cur ^ 1][j] = hn;
            encb[(size_t)t * HH + j] = hn;
        }
        __syncthreads();
        cur ^= 1;
        xc = xn;
    }
}

// ---------------- K3: heads + tridiagonal fill ----------------
// One block per (b,t). 32 groups of 8 lanes each compute one 256-dot.
__global__ __launch_bounds__(256) void head_kernel(
    const float* __restrict__ enc,
    const float* __restrict__ W_mean, const float* __restrict__ b_mean,
    const float* __restrict__ W_bd, const float* __restrict__ b_bd,
    float* __restrict__ mean_out, float* __restrict__ prec)
{
    const int b = blockIdx.x >> 9;
    const int t = blockIdx.x & (TT - 1);
    __shared__ __align__(16) float4 ec[HH / 4];
    __shared__ __align__(16) float4 ep[HH / 4];
    __shared__ float vals[32];

    const int tid = threadIdx.x;
    const float* encb = enc + ((size_t)b * TT + t) * HH;
    if (tid < 64) {
        ec[tid] = ((const float4*)encb)[tid];
    } else if (tid < 128) {
        if (t > 0) ep[tid - 64] = ((const float4*)(encb - HH))[tid - 64];
    }
    __syncthreads();

    const int g = tid >> 3, m = tid & 7;
    const float* wrow;
    float bias;
    const float4* src;
    if (g < 8) {
        wrow = W_mean + (size_t)g * HH; bias = b_mean[g]; src = ec;
    } else if (g < 24) {
        wrow = W_bd + (size_t)(g - 8) * HH; bias = b_bd[g - 8]; src = ec;
    } else {
        wrow = W_bd + (size_t)(g - 16) * HH; bias = b_bd[g - 16]; src = ep;
    }

    float acc = 0.f;
    if (g < 24 || t > 0) {
        const float4* w4 = (const float4*)wrow;
#pragma unroll
        for (int i = 0; i < 8; ++i) {
            const float4 wv = w4[m * 8 + i];
            const float4 hv = src[m * 8 + i];
            acc += wv.x * hv.x + wv.y * hv.y + wv.z * hv.z + wv.w * hv.w;
        }
    }
    acc += __shfl_xor(acc, 1);
    acc += __shfl_xor(acc, 2);
    acc += __shfl_xor(acc, 4);
    if (m == 0) vals[g] = acc + bias;
    __syncthreads();

    if (tid < DD) {
        mean_out[((size_t)b * TT + t) * DD + tid] = vals[tid];
    } else if (tid < 2 * DD) {
        const int d = tid - DD;
        const float diag = vals[8 + d];
        const float off = vals[16 + d];
        const float offp = (t > 0) ? vals[24 + d] : 0.f;
        const size_t rowbase = (((size_t)b * DD + d) * TT + t) * TT;
        prec[rowbase + t] = diag * diag + offp * offp + EPSF;
        if (t < TT - 1) {
            const float s = diag * off;
            prec[rowbase + t + 1] = s;                                 // (t, t+1)
            prec[(((size_t)b * DD + d) * TT + (t + 1)) * TT + t] = s;  // (t+1, t)
        }
    }
}

extern "C" void kernel_launch(void* const* d_in, const int* in_sizes, int n_in,
                              void* d_out, int out_size, void* d_ws, size_t ws_size,
                              hipStream_t stream) {
    const float* y      = (const float*)d_in[0];
    const float* W_ih   = (const float*)d_in[1];
    const float* W_hh   = (const float*)d_in[2];
    const float* b_ih   = (const float*)d_in[3];
    const float* b_hh   = (const float*)d_in[4];
    const float* W_mean = (const float*)d_in[5];
    const float* b_mean = (const float*)d_in[6];
    const float* W_bd   = (const float*)d_in[7];
    const float* b_bd   = (const float*)d_in[8];

    float* out  = (float*)d_out;
    float* mean = out;                              // B*T*D = 65536 floats
    float* prec = out + (size_t)BB * TT * DD;       // B*D*T*T floats

    float* xp  = (float*)d_ws;                      // B*T*H floats = 8 MB
    float* enc = xp + (size_t)BB * TT * HH;         // B*T*H floats = 8 MB

    xproj_kernel<<<512, 512, 0, stream>>>(y, W_ih, b_ih, b_hh, xp);
    scan_fill_kernel<<<240, 1024, 0, stream>>>(xp, W_hh, enc, prec);
    head_kernel<<<BB * TT, 256, 0, stream>>>(enc, W_mean, b_mean, W_bd, b_bd, mean, prec);
}

// Round 3
// 578.815 us; speedup vs baseline: 3.2374x; 1.0034x over previous
//
#include <hip/hip_runtime.h>
#include <math.h>

#define BB 16
#define TT 512
#define IND 128
#define HH 256
#define DD 8
#define EPSF 1e-5f

__device__ __forceinline__ float fast_tanh(float x) {
    x = fminf(fmaxf(x, -15.f), 15.f);
    const float e = __expf(2.f * x);
    return __fdividef(e - 1.f, e + 1.f);
}

// ---------------- K1: x_proj[b,t,j] = y[b,t,:]·W_ih[j,:] + b_ih[j] + b_hh[j] ----------------
// 512 threads: j = tid>>1 (output), k = tid&1 (dot split). 16 NAMED float4 registers hold
// 64 floats of W_ih per thread (macro-unrolled — no array, so nothing can fall to scratch).
__global__ __launch_bounds__(512, 4) void xproj_kernel(
    const float* __restrict__ y, const float* __restrict__ W_ih,
    const float* __restrict__ b_ih, const float* __restrict__ b_hh,
    float* __restrict__ xp)
{
    __shared__ __align__(16) float ylds[IND];
    const int tid = threadIdx.x;
    const int j = tid >> 1;
    const int k4 = (tid & 1) * 4;

    const float* wr = W_ih + (size_t)j * IND + k4;
#define XLOADW(n) const float4 w##n = *(const float4*)(wr + (n) * 8);
    XLOADW(0) XLOADW(1) XLOADW(2) XLOADW(3) XLOADW(4) XLOADW(5) XLOADW(6) XLOADW(7)
    XLOADW(8) XLOADW(9) XLOADW(10) XLOADW(11) XLOADW(12) XLOADW(13) XLOADW(14) XLOADW(15)
#undef XLOADW
    const float bias = b_ih[j] + b_hh[j];

    const int row0 = blockIdx.x * 16;
    for (int r = 0; r < 16; ++r) {
        const int row = row0 + r;
        if (tid < IND / 4) ((float4*)ylds)[tid] = ((const float4*)(y + (size_t)row * IND))[tid];
        __syncthreads();
        float a0 = 0.f, a1 = 0.f, a2 = 0.f, a3 = 0.f;
#define XFMA(n) { const float4 hv = *(const float4*)(ylds + (n) * 8 + k4); \
        a0 = fmaf(hv.x, w##n.x, a0); a1 = fmaf(hv.y, w##n.y, a1); \
        a2 = fmaf(hv.z, w##n.z, a2); a3 = fmaf(hv.w, w##n.w, a3); }
        XFMA(0) XFMA(1) XFMA(2) XFMA(3) XFMA(4) XFMA(5) XFMA(6) XFMA(7)
        XFMA(8) XFMA(9) XFMA(10) XFMA(11) XFMA(12) XFMA(13) XFMA(14) XFMA(15)
#undef XFMA
        float acc = (a0 + a1) + (a2 + a3);
        acc += __shfl_xor(acc, 1);
        if ((tid & 1) == 0) xp[(size_t)row * HH + j] = acc + bias;
        __syncthreads();
    }
}

// ---------------- K2: RNN scan (blocks 0..15) + prec zero-fill (blocks 16..) ----------------
// One block per batch, 1024 threads: j = tid>>2 (output element), k = tid&3 (dot split).
// Thread (j,k) holds W_hh[j, 16i+4k+e] in 16 NAMED float4 registers (64 VGPRs, macro-
// unrolled so SROA can't fail). h double-buffered in LDS; within a wave all 16 j-groups
// read the same 4 addresses -> broadcast, conflict-free. Two shfl_xor combine the 4
// partials; one barrier per step.
__global__ __launch_bounds__(1024, 4) void scan_fill_kernel(
    const float* __restrict__ xp, const float* __restrict__ W_hh,
    float* __restrict__ enc, float* __restrict__ prec)
{
    if (blockIdx.x >= BB) {
        const size_t n4 = (size_t)BB * DD * TT * TT / 4;
        const float4 z = make_float4(0.f, 0.f, 0.f, 0.f);
        float4* p4 = (float4*)prec;
        size_t idx = (size_t)(blockIdx.x - BB) * blockDim.x + threadIdx.x;
        const size_t stride = (size_t)(gridDim.x - BB) * blockDim.x;
        for (; idx < n4; idx += stride) p4[idx] = z;
        return;
    }

    const int b = blockIdx.x;
    const int tid = threadIdx.x;
    const int j = tid >> 2;
    const int k4 = (tid & 3) * 4;
    __shared__ __align__(16) float hbuf0[HH];
    __shared__ __align__(16) float hbuf1[HH];

    const float* wr = W_hh + (size_t)j * HH + k4;
#define SLOADW(n) const float4 w##n = *(const float4*)(wr + (n) * 16);
    SLOADW(0) SLOADW(1) SLOADW(2) SLOADW(3) SLOADW(4) SLOADW(5) SLOADW(6) SLOADW(7)
    SLOADW(8) SLOADW(9) SLOADW(10) SLOADW(11) SLOADW(12) SLOADW(13) SLOADW(14) SLOADW(15)
#undef SLOADW

    if (tid < HH) hbuf0[tid] = 0.f;
    __syncthreads();

    const float* xpb = xp + (size_t)b * TT * HH;
    float* encb = enc + (size_t)b * TT * HH;

    const float* hrd = hbuf0;
    float* hwr = hbuf1;
    float xc = xpb[j];  // t = 0
    for (int t = 0; t < TT; ++t) {
        const int tn = (t < TT - 1) ? t + 1 : t;
        const float xn = xpb[(size_t)tn * HH + j];  // prefetch next x

        float a0 = 0.f, a1 = 0.f, a2 = 0.f, a3 = 0.f;
#define SFMA(n) { const float4 hv = *(const float4*)(hrd + (n) * 16 + k4); \
        a0 = fmaf(hv.x, w##n.x, a0); a1 = fmaf(hv.y, w##n.y, a1); \
        a2 = fmaf(hv.z, w##n.z, a2); a3 = fmaf(hv.w, w##n.w, a3); }
        SFMA(0) SFMA(1) SFMA(2) SFMA(3) SFMA(4) SFMA(5) SFMA(6) SFMA(7)
        SFMA(8) SFMA(9) SFMA(10) SFMA(11) SFMA(12) SFMA(13) SFMA(14) SFMA(15)
#undef SFMA
        float p = (a0 + a1) + (a2 + a3);
        p += __shfl_xor(p, 1);
        p += __shfl_xor(p, 2);
        const float hn = fast_tanh(xc + p);
        if (k4 == 0) {
            hwr[j] = hn;
            encb[(size_t)t * HH + j] = hn;
        }
        __syncthreads();
        const float* tmp = hrd; hrd = hwr; hwr = (float*)tmp;
        xc = xn;
    }
}

// ---------------- K3: heads + tridiagonal fill ----------------
// One block per (b,t). 32 groups of 8 lanes each compute one 256-dot.
__global__ __launch_bounds__(256) void head_kernel(
    const float* __restrict__ enc,
    const float* __restrict__ W_mean, const float* __restrict__ b_mean,
    const float* __restrict__ W_bd, const float* __restrict__ b_bd,
    float* __restrict__ mean_out, float* __restrict__ prec)
{
    const int b = blockIdx.x >> 9;
    const int t = blockIdx.x & (TT - 1);
    __shared__ __align__(16) float4 ec[HH / 4];
    __shared__ __align__(16) float4 ep[HH / 4];
    __shared__ float vals[32];

    const int tid = threadIdx.x;
    const float* encb = enc + ((size_t)b * TT + t) * HH;
    if (tid < 64) {
        ec[tid] = ((const float4*)encb)[tid];
    } else if (tid < 128) {
        if (t > 0) ep[tid - 64] = ((const float4*)(encb - HH))[tid - 64];
    }
    __syncthreads();

    const int g = tid >> 3, m = tid & 7;
    const float* wrow;
    float bias;
    const float4* src;
    if (g < 8) {
        wrow = W_mean + (size_t)g * HH; bias = b_mean[g]; src = ec;
    } else if (g < 24) {
        wrow = W_bd + (size_t)(g - 8) * HH; bias = b_bd[g - 8]; src = ec;
    } else {
        wrow = W_bd + (size_t)(g - 16) * HH; bias = b_bd[g - 16]; src = ep;
    }

    float acc = 0.f;
    if (g < 24 || t > 0) {
        const float4* w4 = (const float4*)wrow;
#pragma unroll
        for (int i = 0; i < 8; ++i) {
            const float4 wv = w4[m * 8 + i];
            const float4 hv = src[m * 8 + i];
            acc += wv.x * hv.x + wv.y * hv.y + wv.z * hv.z + wv.w * hv.w;
        }
    }
    acc += __shfl_xor(acc, 1);
    acc += __shfl_xor(acc, 2);
    acc += __shfl_xor(acc, 4);
    if (m == 0) vals[g] = acc + bias;
    __syncthreads();

    if (tid < DD) {
        mean_out[((size_t)b * TT + t) * DD + tid] = vals[tid];
    } else if (tid < 2 * DD) {
        const int d = tid - DD;
        const float diag = vals[8 + d];
        const float off = vals[16 + d];
        const float offp = (t > 0) ? vals[24 + d] : 0.f;
        const size_t rowbase = (((size_t)b * DD + d) * TT + t) * TT;
        prec[rowbase + t] = diag * diag + offp * offp + EPSF;
        if (t < TT - 1) {
            const float s = diag * off;
            prec[rowbase + t + 1] = s;                                 // (t, t+1)
            prec[(((size_t)b * DD + d) * TT + (t + 1)) * TT + t] = s;  // (t+1, t)
        }
    }
}

extern "C" void kernel_launch(void* const* d_in, const int* in_sizes, int n_in,
                              void* d_out, int out_size, void* d_ws, size_t ws_size,
                              hipStream_t stream) {
    const float* y      = (const float*)d_in[0];
    const float* W_ih   = (const float*)d_in[1];
    const float* W_hh   = (const float*)d_in[2];
    const float* b_ih   = (const float*)d_in[3];
    const float* b_hh   = (const float*)d_in[4];
    const float* W_mean = (const float*)d_in[5];
    const float* b_mean = (const float*)d_in[6];
    const float* W_bd   = (const float*)d_in[7];
    const float* b_bd   = (const float*)d_in[8];

    float* out  = (float*)d_out;
    float* mean = out;                              // B*T*D = 65536 floats
    float* prec = out + (size_t)BB * TT * DD;       // B*D*T*T floats

    float* xp  = (float*)d_ws;                      // B*T*H floats = 8 MB
    float* enc = xp + (size_t)BB * TT * HH;         // B*T*H floats = 8 MB

    xproj_kernel<<<512, 512, 0, stream>>>(y, W_ih, b_ih, b_hh, xp);
    scan_fill_kernel<<<240, 1024, 0, stream>>>(xp, W_hh, enc, prec);
    head_kernel<<<BB * TT, 256, 0, stream>>>(enc, W_mean, b_mean, W_bd, b_bd, mean, prec);
}

// Round 4
// 534.206 us; speedup vs baseline: 3.5077x; 1.0835x over previous
//
#include <hip/hip_runtime.h>
#include <math.h>

#define BB 16
#define TT 512
#define IND 128
#define HH 256
#define DD 8
#define EPSF 1e-5f

typedef _Float16 h2_t __attribute__((ext_vector_type(2)));

__device__ __forceinline__ float fast_tanh(float x) {
    x = fminf(fmaxf(x, -15.f), 15.f);
    const float e = __expf(2.f * x);
    return __fdividef(e - 1.f, e + 1.f);
}

// ---------------- K1: x_proj[b,t,j] = y[b,t,:]·W_ih[j,:] + b_ih[j] + b_hh[j] ----------------
// 512 threads: j = tid>>1, k = tid&1. Weights pinned in VGPRs with opaque asm so the
// allocator cannot sink the loads back into the row loop.
__global__ __launch_bounds__(512, 4) void xproj_kernel(
    const float* __restrict__ y, const float* __restrict__ W_ih,
    const float* __restrict__ b_ih, const float* __restrict__ b_hh,
    float* __restrict__ xp)
{
    __shared__ __align__(16) float ylds[IND];
    const int tid = threadIdx.x;
    const int j = tid >> 1;
    const int k4 = (tid & 1) * 4;

    float4 w[16];
    const float* wr = W_ih + (size_t)j * IND + k4;
#pragma unroll
    for (int i = 0; i < 16; ++i) w[i] = *(const float4*)(wr + i * 8);
#pragma unroll
    for (int i = 0; i < 16; ++i)
        asm volatile("" : "+v"(w[i].x), "+v"(w[i].y), "+v"(w[i].z), "+v"(w[i].w));
    const float bias = b_ih[j] + b_hh[j];

    const int row0 = blockIdx.x * 16;
    for (int r = 0; r < 16; ++r) {
        const int row = row0 + r;
        if (tid < IND / 4) ((float4*)ylds)[tid] = ((const float4*)(y + (size_t)row * IND))[tid];
        __syncthreads();
        float a0 = 0.f, a1 = 0.f, a2 = 0.f, a3 = 0.f;
#pragma unroll
        for (int i = 0; i < 16; ++i) {
            const float4 hv = *(const float4*)(ylds + i * 8 + k4);
            a0 = fmaf(hv.x, w[i].x, a0);
            a1 = fmaf(hv.y, w[i].y, a1);
            a2 = fmaf(hv.z, w[i].z, a2);
            a3 = fmaf(hv.w, w[i].w, a3);
        }
        float acc = (a0 + a1) + (a2 + a3);
        acc += __shfl_xor(acc, 1);
        if ((tid & 1) == 0) xp[(size_t)row * HH + j] = acc + bias;
        __syncthreads();
    }
}

// ---------------- K2: RNN scan (blocks 0..15) + prec zero-fill (blocks 16..) ----------------
// One block per batch, 1024 threads: j = tid>>2 (output), k = tid&3 (contiguous 64-wide
// dot slice). Weights converted to f16 pairs (32 h2 = 32 VGPRs), pinned via opaque asm.
// Inner product uses v_dot2_f32_f16 (2 MACs/instr). h kept in LDS as f16, each k-slice
// padded +16B so the 4 distinct wave addresses land on different banks.
__global__ __launch_bounds__(1024, 4) void scan_fill_kernel(
    const float* __restrict__ xp, const float* __restrict__ W_hh,
    float* __restrict__ enc, float* __restrict__ prec)
{
    if (blockIdx.x >= BB) {
        const size_t n4 = (size_t)BB * DD * TT * TT / 4;
        const float4 z = make_float4(0.f, 0.f, 0.f, 0.f);
        float4* p4 = (float4*)prec;
        size_t idx = (size_t)(blockIdx.x - BB) * blockDim.x + threadIdx.x;
        const size_t stride = (size_t)(gridDim.x - BB) * blockDim.x;
        for (; idx < n4; idx += stride) p4[idx] = z;
        return;
    }

    const int b = blockIdx.x;
    const int tid = threadIdx.x;
    const int j = tid >> 2;
    const int k = tid & 3;

    // each k-slice: 64 halves = 128 B, padded to 144 B
    __shared__ __align__(16) char hbufA[4 * 144];
    __shared__ __align__(16) char hbufB[4 * 144];

    // weights: W_hh[j, k*64 + m], m = 0..63, packed as 32 f16-pairs
    h2_t w[32];
    {
        const float* wr = W_hh + (size_t)j * HH + (size_t)k * 64;
#pragma unroll
        for (int i = 0; i < 32; ++i) {
            h2_t v;
            v.x = (_Float16)wr[2 * i];
            v.y = (_Float16)wr[2 * i + 1];
            w[i] = v;
        }
    }
#pragma unroll
    for (int i = 0; i < 32; ++i) {
        int tmp = __builtin_bit_cast(int, w[i]);
        asm volatile("" : "+v"(tmp));
        w[i] = __builtin_bit_cast(h2_t, tmp);
    }

    // zero-init hbufA (pads don't matter: never read)
    if (tid < 128) {
        const int m = 2 * tid;
        h2_t z; z.x = (_Float16)0.f; z.y = (_Float16)0.f;
        *(h2_t*)(hbufA + (m >> 6) * 144 + (m & 63) * 2) = z;
    }
    __syncthreads();

    const float* xpb = xp + (size_t)b * TT * HH;
    float* encb = enc + (size_t)b * TT * HH;

    const char* hrd = hbufA;
    char* hwr = hbufB;
    float xc = xpb[j];  // t = 0
    for (int t = 0; t < TT; ++t) {
        const int tn = (t < TT - 1) ? t + 1 : t;
        const float xn = xpb[(size_t)tn * HH + j];  // prefetch next x

        float a0 = 0.f, a1 = 0.f, a2 = 0.f, a3 = 0.f;
        const float4* hp = (const float4*)(hrd + k * 144);
#pragma unroll
        for (int i = 0; i < 8; ++i) {
            union { float4 f4; h2_t h[4]; } u;
            u.f4 = hp[i];
            a0 = __builtin_amdgcn_fdot2(u.h[0], w[4 * i + 0], a0, false);
            a1 = __builtin_amdgcn_fdot2(u.h[1], w[4 * i + 1], a1, false);
            a2 = __builtin_amdgcn_fdot2(u.h[2], w[4 * i + 2], a2, false);
            a3 = __builtin_amdgcn_fdot2(u.h[3], w[4 * i + 3], a3, false);
        }
        float p = (a0 + a1) + (a2 + a3);
        p += __shfl_xor(p, 1);
        p += __shfl_xor(p, 2);
        const float hn = fast_tanh(xc + p);
        const float hnp = __shfl_xor(hn, 4);  // partner j^1 (same k)
        if (k == 0) {
            encb[(size_t)t * HH + j] = hn;
            if ((j & 1) == 0) {
                h2_t hv; hv.x = (_Float16)hn; hv.y = (_Float16)hnp;
                *(h2_t*)(hwr + (j >> 6) * 144 + (j & 63) * 2) = hv;
            }
        }
        __syncthreads();
        const char* tmp = hrd; hrd = hwr; hwr = (char*)tmp;
        xc = xn;
    }
}

// ---------------- K3: heads + tridiagonal fill ----------------
// 1024 blocks: each handles one b and 8 consecutive t. 9 enc rows staged in LDS once;
// per t, 32 groups of 8 lanes compute the 24 distinct dots; single barrier before the
// scatter-write phase.
__global__ __launch_bounds__(256) void head_kernel(
    const float* __restrict__ enc,
    const float* __restrict__ W_mean, const float* __restrict__ b_mean,
    const float* __restrict__ W_bd, const float* __restrict__ b_bd,
    float* __restrict__ mean_out, float* __restrict__ prec)
{
    const int b = blockIdx.x >> 6;
    const int t0 = (blockIdx.x & 63) * 8;
    __shared__ __align__(16) float erow[9][HH];  // rows t0-1 .. t0+7
    __shared__ float vals[8][32];

    const int tid = threadIdx.x;
    {
        // row t0-1 (for t0==0,b==0 this reads the tail of xp — harmless, discarded)
        const float4* src = (const float4*)(enc + ((size_t)b * TT + t0) * HH - HH);
        float4* dst = (float4*)erow;
        for (int i = tid; i < 9 * (HH / 4); i += 256) dst[i] = src[i];
    }

    const int g = tid >> 3, m = tid & 7;
    const float* wrow;
    float bias;
    if (g < 8)       { wrow = W_mean + (size_t)g * HH;      bias = b_mean[g]; }
    else if (g < 24) { wrow = W_bd + (size_t)(g - 8) * HH;  bias = b_bd[g - 8]; }
    else             { wrow = W_bd + (size_t)(g - 16) * HH; bias = b_bd[g - 16]; }

    float4 wv[8];
#pragma unroll
    for (int i = 0; i < 8; ++i) wv[i] = ((const float4*)wrow)[m * 8 + i];

    __syncthreads();

    for (int r = 0; r < 8; ++r) {
        const float* src = (g >= 24) ? erow[r] : erow[r + 1];
        float acc = 0.f;
#pragma unroll
        for (int i = 0; i < 8; ++i) {
            const float4 hv = ((const float4*)src)[m * 8 + i];
            acc += wv[i].x * hv.x + wv[i].y * hv.y + wv[i].z * hv.z + wv[i].w * hv.w;
        }
        acc += __shfl_xor(acc, 1);
        acc += __shfl_xor(acc, 2);
        acc += __shfl_xor(acc, 4);
        if (m == 0) vals[r][g] = acc + bias;
    }
    __syncthreads();

    // write phase: 256 threads = 8 r-slots x 32 lanes
    const int r = tid >> 5, s = tid & 31;
    const int t = t0 + r;
    if (s < DD) {
        mean_out[((size_t)b * TT + t) * DD + s] = vals[r][s];
    } else if (s < 2 * DD) {
        const int d = s - DD;
        const float diag = vals[r][8 + d];
        const float off  = vals[r][16 + d];
        const float offp = (t > 0) ? vals[r][24 + d] : 0.f;
        const size_t rowbase = (((size_t)b * DD + d) * TT + t) * TT;
        prec[rowbase + t] = diag * diag + offp * offp + EPSF;
        if (t < TT - 1) {
            const float sv = diag * off;
            prec[rowbase + t + 1] = sv;                                 // (t, t+1)
            prec[(((size_t)b * DD + d) * TT + (t + 1)) * TT + t] = sv;  // (t+1, t)
        }
    }
}

extern "C" void kernel_launch(void* const* d_in, const int* in_sizes, int n_in,
                              void* d_out, int out_size, void* d_ws, size_t ws_size,
                              hipStream_t stream) {
    const float* y      = (const float*)d_in[0];
    const float* W_ih   = (const float*)d_in[1];
    const float* W_hh   = (const float*)d_in[2];
    const float* b_ih   = (const float*)d_in[3];
    const float* b_hh   = (const float*)d_in[4];
    const float* W_mean = (const float*)d_in[5];
    const float* b_mean = (const float*)d_in[6];
    const float* W_bd   = (const float*)d_in[7];
    const float* b_bd   = (const float*)d_in[8];

    float* out  = (float*)d_out;
    float* mean = out;                              // B*T*D floats
    float* prec = out + (size_t)BB * TT * DD;       // B*D*T*T floats

    float* xp  = (float*)d_ws;                      // B*T*H floats = 8 MB
    float* enc = xp + (size_t)BB * TT * HH;         // B*T*H floats = 8 MB

    xproj_kernel<<<512, 512, 0, stream>>>(y, W_ih, b_ih, b_hh, xp);
    scan_fill_kernel<<<240, 1024, 0, stream>>>(xp, W_hh, enc, prec);
    head_kernel<<<1024, 256, 0, stream>>>(enc, W_mean, b_mean, W_bd, b_bd, mean, prec);
}